// Round 3
// baseline (607.219 us; speedup 1.0000x reference)
//
#include <hip/hip_runtime.h>

// Problem: B=8, C=16, H=32, W=32 -> N=1024, Ho=Wo=16, P=256
// d_out layout: mu_p [128*256 f32] then sigma_p [128*256*256 f32]
//
// R3: coalesced row staging. Each block owns 32 output rows of one (b,c).
// A 4-row chunk of sigma rows is staged to LDS via float4 loads (wave q
// stages row q, 16B/lane fully coalesced); the column gather is resolved in
// LDS (bank spread ~2 lanes/bank -> conflict-free); 4B coalesced stores.
// Double-buffered: next chunk's global loads are issued before the current
// chunk's gather, ds_write afterwards, so HBM latency overlaps LDS work.

#define BC    128
#define WDIM  32
#define NP    256
#define NN    1024
#define ROWS_PER_BLOCK 32
#define CHUNK 4
#define NCHUNK (ROWS_PER_BLOCK / CHUNK)   // 8

__global__ __launch_bounds__(256) void fused_kernel(
    const float* __restrict__ mu,
    const float* __restrict__ sigma,
    float* __restrict__ out_mu,     // [BC*NP]
    float* __restrict__ out_sigma)  // [BC*NP*NP]
{
    int bc = blockIdx.x >> 3;                    // 0..127
    int i0 = (blockIdx.x & 7) * ROWS_PER_BLOCK;  // 0,32,..,224
    int t  = threadIdx.x;

    __shared__ int    s_idx[NP];
    __shared__ float4 s_row[2][CHUNK * (NN / 4)];   // 2 x 16 KB

    // --- pool + first-occurrence argmax (redundant x8 blocks; mu is L2-hot) ---
    {
        int ho = t >> 4, wo = t & 15;
        const float* m = mu + (size_t)bc * NN;
        int r0 = 2 * ho, c0 = 2 * wo;
        float v00 = m[r0 * WDIM + c0];
        float v01 = m[r0 * WDIM + c0 + 1];
        float v10 = m[(r0 + 1) * WDIM + c0];
        float v11 = m[(r0 + 1) * WDIM + c0 + 1];
        float best = v00; int k = 0;
        if (v01 > best) { best = v01; k = 1; }
        if (v10 > best) { best = v10; k = 2; }
        if (v11 > best) { best = v11; k = 3; }
        s_idx[t] = (r0 + (k >> 1)) * WDIM + (c0 + (k & 1));
        if (i0 == 0) out_mu[bc * NP + t] = best;
    }
    __syncthreads();

    const float* sg     = sigma + (size_t)bc * NN * NN;
    const float* s_rowF = (const float*)s_row;
    int cj   = s_idx[t];        // this thread's output column index
    int q    = t >> 6;          // wave id: stages row q of each chunk
    int lane = t & 63;

    float4 reg0, reg1, reg2, reg3;

    // prologue: load + stage chunk 0 into buffer 0
    {
        int ri = s_idx[i0 + q];
        const float4* src = (const float4*)(sg + (size_t)ri * NN);
        reg0 = src[lane];
        reg1 = src[lane + 64];
        reg2 = src[lane + 128];
        reg3 = src[lane + 192];
        float4* dst = &s_row[0][q * (NN / 4)];
        dst[lane]       = reg0;
        dst[lane + 64]  = reg1;
        dst[lane + 128] = reg2;
        dst[lane + 192] = reg3;
    }

    for (int c = 0; c < NCHUNK; ++c) {
        __syncthreads();
        // issue next chunk's global loads (in flight during gather)
        if (c + 1 < NCHUNK) {
            int ri = s_idx[i0 + (c + 1) * CHUNK + q];
            const float4* src = (const float4*)(sg + (size_t)ri * NN);
            reg0 = src[lane];
            reg1 = src[lane + 64];
            reg2 = src[lane + 128];
            reg3 = src[lane + 192];
        }
        // gather current chunk from LDS, coalesced 4B stores
        const float* buf = s_rowF + (size_t)(c & 1) * CHUNK * NN;
        float* ob = out_sigma + ((size_t)bc * NP + i0 + c * CHUNK) * NP;
#pragma unroll
        for (int qq = 0; qq < CHUNK; ++qq) {
            ob[qq * NP + t] = buf[qq * NN + cj];
        }
        // stage next chunk into the other buffer
        if (c + 1 < NCHUNK) {
            float4* dst = &s_row[(c + 1) & 1][q * (NN / 4)];
            dst[lane]       = reg0;
            dst[lane + 64]  = reg1;
            dst[lane + 128] = reg2;
            dst[lane + 192] = reg3;
        }
    }
}

extern "C" void kernel_launch(void* const* d_in, const int* in_sizes, int n_in,
                              void* d_out, int out_size, void* d_ws, size_t ws_size,
                              hipStream_t stream) {
    const float* mu    = (const float*)d_in[0];
    const float* sigma = (const float*)d_in[1];
    float* out = (float*)d_out;
    fused_kernel<<<1024, 256, 0, stream>>>(mu, sigma, out, out + BC * NP);
}